// Round 1
// baseline (23866.385 us; speedup 1.0000x reference)
//
#include <hip/hip_runtime.h>
#include <hip/hip_bf16.h>
#include <math.h>

#define DEV __device__ __forceinline__

typedef __attribute__((ext_vector_type(4))) float f32x4;
typedef __attribute__((ext_vector_type(8))) short bf16x8;
typedef __attribute__((ext_vector_type(4))) short s16x4;

static constexpr int Bz = 32, Lz = 400, Cz = 1024, MLPz = 4096;
static constexpr int BL = Bz * Lz;  // 12800

DEV float bf2f(unsigned short u) {
  union { unsigned int i; float f; } v; v.i = ((unsigned int)u) << 16; return v.f;
}
DEV unsigned short f2bf(float f) {
  union { float f; unsigned int i; } v; v.f = f;
  unsigned int r = v.i + 0x7FFFu + ((v.i >> 16) & 1u);
  return (unsigned short)(r >> 16);
}

DEV int level_of(int l) {
  const int cum[13] = {1,3,6,10,16,25,38,57,84,124,184,272,400};
  int lv = 12;
  #pragma unroll
  for (int i = 12; i >= 0; i--) if (l < cum[i]) lv = i;
  return lv;
}
DEV int row_kmax(int l) {
  const int cum[13] = {1,3,6,10,16,25,38,57,84,124,184,272,400};
  int km = 400;
  #pragma unroll
  for (int i = 12; i >= 0; i--) if (l < cum[i]) km = cum[i];
  return km;
}

// ---------------------------------------------------------------- GEMM
// C[M,N] = A[M,K](bf16) @ Bw[K,N](f32, converted inline) + bias
// 128x128 tile, BK=64, 4 waves (2x2), 16x16x32 bf16 MFMA, XOR-swizzled LDS.
enum { EP_BF16 = 0, EP_GELU = 1, EP_RESID = 2, EP_F32 = 3 };

template<int MODE>
__global__ __launch_bounds__(256, 2)
void gemm_k(const unsigned short* __restrict__ A, const float* __restrict__ Bw,
            const float* __restrict__ bias, void* __restrict__ out,
            float* __restrict__ xres, const float* __restrict__ gsh,
            const float* __restrict__ gpb, int N, int K)
{
  __shared__ unsigned short As[128 * 64];
  __shared__ unsigned short Bs[128 * 64];
  const int tid = threadIdx.x;
  const int lane = tid & 63, wv = tid >> 6;
  const int row0 = blockIdx.x * 128, col0 = blockIdx.y * 128;
  const int wm = (wv >> 1) * 64, wn = (wv & 1) * 64;

  f32x4 acc[4][4];
  #pragma unroll
  for (int i = 0; i < 4; i++)
    #pragma unroll
    for (int j = 0; j < 4; j++) acc[i][j] = (f32x4){0.f, 0.f, 0.f, 0.f};

  const int bn = tid & 127;            // B staging: output col within tile
  const int kslab = (tid >> 7) * 32;   // B staging: k slab

  for (int k0 = 0; k0 < K; k0 += 64) {
    // ---- stage A tile: [128 rows][64 k] bf16, 16B chunks, swizzled
    #pragma unroll
    for (int i = 0; i < 4; i++) {
      int chunk = i * 256 + tid;
      int r = chunk >> 3, c8 = chunk & 7;
      bf16x8 v = *(const bf16x8*)(A + (size_t)(row0 + r) * K + k0 + c8 * 8);
      *(bf16x8*)((char*)As + r * 128 + ((c8 * 16) ^ ((r & 7) << 4))) = v;
    }
    // ---- stage B tile transposed: Bs[n][k] bf16 from f32 [k][n]
    #pragma unroll
    for (int i = 0; i < 8; i++) {
      int kq = kslab + i * 4;
      const float* bp = Bw + (size_t)(k0 + kq) * N + col0 + bn;
      float f0 = bp[0];
      float f1 = bp[(size_t)N];
      float f2 = bp[2 * (size_t)N];
      float f3 = bp[3 * (size_t)N];
      s16x4 w4;
      w4[0] = (short)f2bf(f0); w4[1] = (short)f2bf(f1);
      w4[2] = (short)f2bf(f2); w4[3] = (short)f2bf(f3);
      *(s16x4*)((char*)Bs + bn * 128 + ((kq * 2) ^ ((bn & 7) << 4))) = w4;
    }
    __syncthreads();
    // ---- MFMA
    #pragma unroll
    for (int kk = 0; kk < 2; kk++) {
      bf16x8 af[4], bfr[4];
      const int bcol = kk * 64 + (lane >> 4) * 16;
      #pragma unroll
      for (int m = 0; m < 4; m++) {
        int r = wm + m * 16 + (lane & 15);
        af[m] = *(const bf16x8*)((char*)As + r * 128 + (bcol ^ ((r & 7) << 4)));
      }
      #pragma unroll
      for (int n = 0; n < 4; n++) {
        int r = wn + n * 16 + (lane & 15);
        bfr[n] = *(const bf16x8*)((char*)Bs + r * 128 + (bcol ^ ((r & 7) << 4)));
      }
      #pragma unroll
      for (int m = 0; m < 4; m++)
        #pragma unroll
        for (int n = 0; n < 4; n++)
          acc[m][n] = __builtin_amdgcn_mfma_f32_16x16x32_bf16(af[m], bfr[n], acc[m][n], 0, 0, 0);
    }
    __syncthreads();
  }

  // ---- epilogue: D row = rbase + m*16 + r ; col = cbase + n*16
  const int rbase = row0 + wm + ((lane >> 4) << 2);
  const int cbase = col0 + wn + (lane & 15);
  #pragma unroll
  for (int n = 0; n < 4; n++) {
    int gcol = cbase + n * 16;
    float bv = bias[gcol];
    #pragma unroll
    for (int m = 0; m < 4; m++) {
      #pragma unroll
      for (int r = 0; r < 4; r++) {
        int grow = rbase + m * 16 + r;
        float v = acc[m][n][r] + bv;
        if constexpr (MODE == EP_BF16) {
          ((unsigned short*)out)[(size_t)grow * N + gcol] = f2bf(v);
        } else if constexpr (MODE == EP_GELU) {
          float g = 0.5f * v * (1.f + erff(v * 0.70710678118654752f));
          ((unsigned short*)out)[(size_t)grow * N + gcol] = f2bf(g);
        } else if constexpr (MODE == EP_RESID) {
          int b = grow / Lz;
          float g = gsh[gcol] + gpb[(size_t)b * 6144 + gcol];
          xres[(size_t)grow * Cz + gcol] += g * v;
        } else {
          ((float*)out)[(size_t)grow * N + gcol] = v;
        }
      }
    }
  }
}

// ---------------------------------------------------------------- LayerNorm (+adaLN scale/shift) -> bf16
__global__ __launch_bounds__(256)
void ln_k(const float* __restrict__ x, unsigned short* __restrict__ out,
          const float* __restrict__ ssh, const float* __restrict__ spb, int sstride,
          const float* __restrict__ hsh, const float* __restrict__ hpb, int hstride)
{
  const int row = blockIdx.x, tid = threadIdx.x;
  const int b = row / Lz;
  const float* xr = x + (size_t)row * Cz;
  float v[4];
  float s = 0.f;
  #pragma unroll
  for (int i = 0; i < 4; i++) { v[i] = xr[tid + i * 256]; s += v[i]; }
  __shared__ float red[8];
  #pragma unroll
  for (int o = 32; o > 0; o >>= 1) s += __shfl_xor(s, o, 64);
  if ((tid & 63) == 0) red[tid >> 6] = s;
  __syncthreads();
  float mean = (red[0] + red[1] + red[2] + red[3]) * (1.f / 1024.f);
  float vs = 0.f;
  #pragma unroll
  for (int i = 0; i < 4; i++) { float d = v[i] - mean; vs += d * d; }
  #pragma unroll
  for (int o = 32; o > 0; o >>= 1) vs += __shfl_xor(vs, o, 64);
  __syncthreads();
  if ((tid & 63) == 0) red[4 + (tid >> 6)] = vs;
  __syncthreads();
  float var = (red[4] + red[5] + red[6] + red[7]) * (1.f / 1024.f);
  float rstd = rsqrtf(var + 1e-6f);
  #pragma unroll
  for (int i = 0; i < 4; i++) {
    int c = tid + i * 256;
    float sc = (ssh ? ssh[c] : 0.f) + spb[(size_t)b * sstride + c];
    float sh = (hsh ? hsh[c] : 0.f) + hpb[(size_t)b * hstride + c];
    out[(size_t)row * Cz + c] = f2bf((v[i] - mean) * rstd * (1.f + sc) + sh);
  }
}

// ---------------------------------------------------------------- attention
// one block per (b,h); K,V staged in LDS; one thread per query row, exact
// softmax over the level-prefix [0, kmax).
__global__ __launch_bounds__(512)
void attn_k(const unsigned short* __restrict__ qb,
            const unsigned short* __restrict__ kvb,
            unsigned short* __restrict__ ob)
{
  __shared__ unsigned short Ks[400 * 68];
  __shared__ unsigned short Vs[400 * 68];
  const int bh = blockIdx.x, b = bh >> 4, h = bh & 15;
  const int tid = threadIdx.x;
  const size_t base = ((size_t)b * Lz) * 2048 + h * 64;
  for (int i = tid; i < 6400; i += 512) {
    int l = i >> 4, d4 = (i & 15) << 2;
    *(s16x4*)&Ks[l * 68 + d4] = *(const s16x4*)&kvb[base + (size_t)l * 2048 + d4];
    *(s16x4*)&Vs[l * 68 + d4] = *(const s16x4*)&kvb[base + (size_t)l * 2048 + 1024 + d4];
  }
  __syncthreads();
  const int row = tid;
  if (row < Lz) {
    const int kmax = row_kmax(row);
    float q[64], o[64];
    const unsigned short* qp = qb + ((size_t)(b * Lz + row)) * Cz + h * 64;
    #pragma unroll
    for (int i = 0; i < 16; i++) {
      s16x4 t = *(const s16x4*)(qp + i * 4);
      q[i*4+0] = bf2f((unsigned short)t[0]) * 0.125f;
      q[i*4+1] = bf2f((unsigned short)t[1]) * 0.125f;
      q[i*4+2] = bf2f((unsigned short)t[2]) * 0.125f;
      q[i*4+3] = bf2f((unsigned short)t[3]) * 0.125f;
    }
    #pragma unroll
    for (int d = 0; d < 64; d++) o[d] = 0.f;
    float m = -1e30f, lsum = 0.f;
    for (int k = 0; k < kmax; k++) {
      const unsigned short* kr = &Ks[k * 68];
      float s = 0.f;
      #pragma unroll
      for (int i = 0; i < 16; i++) {
        s16x4 t = *(const s16x4*)(kr + i * 4);
        s += q[i*4+0] * bf2f((unsigned short)t[0]);
        s += q[i*4+1] * bf2f((unsigned short)t[1]);
        s += q[i*4+2] * bf2f((unsigned short)t[2]);
        s += q[i*4+3] * bf2f((unsigned short)t[3]);
      }
      const unsigned short* vr = &Vs[k * 68];
      if (s <= m) {
        float p = __expf(s - m);
        lsum += p;
        #pragma unroll
        for (int i = 0; i < 16; i++) {
          s16x4 t = *(const s16x4*)(vr + i * 4);
          o[i*4+0] += p * bf2f((unsigned short)t[0]);
          o[i*4+1] += p * bf2f((unsigned short)t[1]);
          o[i*4+2] += p * bf2f((unsigned short)t[2]);
          o[i*4+3] += p * bf2f((unsigned short)t[3]);
        }
      } else {
        float f = __expf(m - s);
        m = s;
        lsum = lsum * f + 1.f;
        #pragma unroll
        for (int i = 0; i < 16; i++) {
          s16x4 t = *(const s16x4*)(vr + i * 4);
          o[i*4+0] = o[i*4+0] * f + bf2f((unsigned short)t[0]);
          o[i*4+1] = o[i*4+1] * f + bf2f((unsigned short)t[1]);
          o[i*4+2] = o[i*4+2] * f + bf2f((unsigned short)t[2]);
          o[i*4+3] = o[i*4+3] * f + bf2f((unsigned short)t[3]);
        }
      }
    }
    float inv = 1.f / lsum;
    unsigned short* op = ob + ((size_t)(b * Lz + row)) * Cz + h * 64;
    #pragma unroll
    for (int d = 0; d < 64; d++) op[d] = f2bf(o[d] * inv);
  }
}

// ---------------------------------------------------------------- preamble
__global__ __launch_bounds__(256)
void cond_k(const float* __restrict__ pc, const float* __restrict__ pw,
            const float* __restrict__ pb, float* __restrict__ cond,
            float* __restrict__ silu)
{
  const int b = blockIdx.y;
  const int n = blockIdx.x * 256 + threadIdx.x;
  __shared__ float a[256];
  a[threadIdx.x] = pc[b * 256 + threadIdx.x];
  __syncthreads();
  float s = pb[n];
  for (int k = 0; k < 256; k++) s += a[k] * pw[(size_t)k * Cz + n];
  cond[(size_t)b * Cz + n] = s;
  silu[(size_t)b * Cz + n] = s / (1.f + __expf(-s));
}

__global__ __launch_bounds__(256)
void smallmm_k(const float* __restrict__ A, const float* __restrict__ W,
               const float* __restrict__ bias, float* __restrict__ out, int N)
{
  const int b = blockIdx.y;
  const int n = blockIdx.x * 256 + threadIdx.x;
  __shared__ float a[1024];
  for (int i = threadIdx.x; i < 1024; i += 256) a[i] = A[(size_t)b * 1024 + i];
  __syncthreads();
  float s = bias[n];
  for (int k = 0; k < 1024; k++) s += a[k] * W[(size_t)k * N + n];
  out[(size_t)b * N + n] = s;
}

// word embedding + lvl/pos add. MODE 0: x init (f32, row 0 special); MODE 1: poc (bf16)
template<int MODE>
__global__ __launch_bounds__(256)
void embed_k(const float* __restrict__ src, const float* __restrict__ ww,
             const float* __restrict__ wb, const float* __restrict__ cond,
             const float* __restrict__ pos_start, const float* __restrict__ pos1,
             const float* __restrict__ ltab, void* __restrict__ out)
{
  const int r0 = blockIdx.x * 4;         // 4 rows per block; 400 % 4 == 0 -> same b
  const int tid = threadIdx.x;
  const int b = r0 / Lz;
  __shared__ float a[4][64];
  {
    int rr = tid >> 6, k = tid & 63;
    int l = (r0 + rr) % Lz;
    float val;
    if (MODE == 0) val = (l == 0) ? 0.f : src[((size_t)b * (Lz - 1) + (l - 1)) * 64 + k];
    else           val = src[((size_t)(r0 + rr)) * 64 + k];
    a[rr][k] = val;
  }
  __syncthreads();
  #pragma unroll
  for (int ci = 0; ci < 4; ci++) {
    int c = tid + ci * 256;
    float s[4];
    #pragma unroll
    for (int rr = 0; rr < 4; rr++) {
      int l = (r0 + rr) % Lz;
      s[rr] = wb[c] + ltab[(size_t)level_of(l) * Cz + c] + pos1[(size_t)l * Cz + c];
    }
    for (int k = 0; k < 64; k++) {
      float w = ww[(size_t)k * Cz + c];
      #pragma unroll
      for (int rr = 0; rr < 4; rr++) s[rr] += a[rr][k] * w;
    }
    #pragma unroll
    for (int rr = 0; rr < 4; rr++) {
      int l = (r0 + rr) % Lz;
      if (MODE == 0) {
        float val = s[rr];
        if (l == 0) val = cond[(size_t)b * Cz + c] + pos_start[c] + ltab[c] + pos1[c];
        ((float*)out)[((size_t)(r0 + rr)) * Cz + c] = val;
      } else {
        ((unsigned short*)out)[((size_t)(r0 + rr)) * Cz + c] = f2bf(s[rr]);
      }
    }
  }
}

// ---------------------------------------------------------------- launch
extern "C" void kernel_launch(void* const* d_in, const int* in_sizes, int n_in,
                              void* d_out, int out_size, void* d_ws, size_t ws_size,
                              hipStream_t stream)
{
  (void)in_sizes; (void)n_in; (void)out_size; (void)ws_size;
  const float* x_blcv   = (const float*)d_in[0];
  const float* poc_ctx  = (const float*)d_in[1];
  const float* poc_cond = (const float*)d_in[2];
  const float* word_w   = (const float*)d_in[3];
  const float* word_b   = (const float*)d_in[4];
  const float* poc_w    = (const float*)d_in[5];
  const float* poc_b    = (const float*)d_in[6];
  const float* pos_start= (const float*)d_in[7];
  const float* pos_1lc  = (const float*)d_in[8];
  const float* lvl_tab  = (const float*)d_in[9];
  const float* ada_w    = (const float*)d_in[10];
  const float* ada_b    = (const float*)d_in[11];
  const float* ada_gss  = (const float*)d_in[12];
  const float* q_w      = (const float*)d_in[13];
  const float* q_b      = (const float*)d_in[14];
  const float* kv_w     = (const float*)d_in[15];
  const float* kv_b     = (const float*)d_in[16];
  const float* proj_w   = (const float*)d_in[17];
  const float* proj_b   = (const float*)d_in[18];
  const float* fc1_w    = (const float*)d_in[19];
  const float* fc1_b    = (const float*)d_in[20];
  const float* fc2_w    = (const float*)d_in[21];
  const float* fc2_b    = (const float*)d_in[22];
  const float* head_ada_w = (const float*)d_in[23];
  const float* head_ada_b = (const float*)d_in[24];
  const float* head_w   = (const float*)d_in[25];
  const float* head_b   = (const float*)d_in[26];

  char* p = (char*)d_ws;
  auto carve = [&](size_t bytes) { void* r = (void*)p; p += (bytes + 255) & ~(size_t)255; return r; };
  float* x            = (float*)carve((size_t)BL * Cz * 4);
  unsigned short* xn  = (unsigned short*)carve((size_t)BL * Cz * 2);
  unsigned short* poc = (unsigned short*)carve((size_t)BL * Cz * 2);
  unsigned short* qbf = (unsigned short*)carve((size_t)BL * Cz * 2);
  unsigned short* kvb = (unsigned short*)carve((size_t)BL * 2 * Cz * 2);
  unsigned short* ob  = (unsigned short*)carve((size_t)BL * Cz * 2);
  unsigned short* hdn = (unsigned short*)carve((size_t)BL * MLPz * 2);
  float* cond  = (float*)carve(32 * 1024 * 4);
  float* siluc = (float*)carve(32 * 1024 * 4);
  float* gss   = (float*)carve(32 * 6144 * 4);
  float* ss    = (float*)carve(32 * 2048 * 4);

  cond_k<<<dim3(4, 32), 256, 0, stream>>>(poc_cond, poc_w, poc_b, cond, siluc);
  smallmm_k<<<dim3(24, 32), 256, 0, stream>>>(siluc, ada_w, ada_b, gss, 6144);
  smallmm_k<<<dim3(8, 32), 256, 0, stream>>>(siluc, head_ada_w, head_ada_b, ss, 2048);
  embed_k<0><<<3200, 256, 0, stream>>>(x_blcv, word_w, word_b, cond, pos_start, pos_1lc, lvl_tab, x);
  embed_k<1><<<3200, 256, 0, stream>>>(poc_ctx, word_w, word_b, cond, pos_start, pos_1lc, lvl_tab, poc);

  for (int d = 0; d < 8; d++) {
    const float* ag = ada_gss + (size_t)d * 6144;
    ln_k<<<BL, 256, 0, stream>>>(x, xn, ag + 2 * 1024, gss + 2 * 1024, 6144,
                                 ag + 4 * 1024, gss + 4 * 1024, 6144);
    gemm_k<EP_BF16><<<dim3(100, 8), 256, 0, stream>>>(
        xn, q_w + (size_t)d * 1024 * 1024, q_b + d * 1024, qbf, nullptr, nullptr, nullptr, 1024, 1024);
    gemm_k<EP_BF16><<<dim3(100, 16), 256, 0, stream>>>(
        poc, kv_w + (size_t)d * 1024 * 2048, kv_b + d * 2048, kvb, nullptr, nullptr, nullptr, 2048, 1024);
    attn_k<<<512, 512, 0, stream>>>(qbf, kvb, ob);
    gemm_k<EP_RESID><<<dim3(100, 8), 256, 0, stream>>>(
        ob, proj_w + (size_t)d * 1024 * 1024, proj_b + d * 1024, nullptr, x, ag + 0, gss + 0, 1024, 1024);
    ln_k<<<BL, 256, 0, stream>>>(x, xn, ag + 3 * 1024, gss + 3 * 1024, 6144,
                                 ag + 5 * 1024, gss + 5 * 1024, 6144);
    gemm_k<EP_GELU><<<dim3(100, 32), 256, 0, stream>>>(
        xn, fc1_w + (size_t)d * 1024 * 4096, fc1_b + d * 4096, hdn, nullptr, nullptr, nullptr, 4096, 1024);
    gemm_k<EP_RESID><<<dim3(100, 8), 256, 0, stream>>>(
        hdn, fc2_w + (size_t)d * 4096 * 1024, fc2_b + d * 1024, nullptr, x, ag + 1024, gss + 1024, 1024, 4096);
  }
  ln_k<<<BL, 256, 0, stream>>>(x, xn, nullptr, ss, 2048, nullptr, ss + 1024, 2048);
  gemm_k<EP_F32><<<dim3(100, 32), 256, 0, stream>>>(
      xn, head_w, head_b, d_out, nullptr, nullptr, nullptr, 4096, 1024);
}

// Round 2
// 7848.074 us; speedup vs baseline: 3.0411x; 3.0411x over previous
//
#include <hip/hip_runtime.h>
#include <hip/hip_bf16.h>
#include <math.h>

#define DEV __device__ __forceinline__

typedef __attribute__((ext_vector_type(4))) float f32x4;
typedef __attribute__((ext_vector_type(8))) short bf16x8;
typedef __attribute__((ext_vector_type(4))) short s16x4;

static constexpr int Bz = 32, Lz = 400, Cz = 1024, MLPz = 4096;
static constexpr int BL = Bz * Lz;  // 12800

DEV float bf2f(unsigned short u) {
  union { unsigned int i; float f; } v; v.i = ((unsigned int)u) << 16; return v.f;
}
DEV unsigned short f2bf(float f) {
  union { float f; unsigned int i; } v; v.f = f;
  unsigned int r = v.i + 0x7FFFu + ((v.i >> 16) & 1u);
  return (unsigned short)(r >> 16);
}

DEV int level_of(int l) {
  const int cum[13] = {1,3,6,10,16,25,38,57,84,124,184,272,400};
  int lv = 12;
  #pragma unroll
  for (int i = 12; i >= 0; i--) if (l < cum[i]) lv = i;
  return lv;
}
DEV int row_kmax(int l) {
  const int cum[13] = {1,3,6,10,16,25,38,57,84,124,184,272,400};
  int km = 400;
  #pragma unroll
  for (int i = 12; i >= 0; i--) if (l < cum[i]) km = cum[i];
  return km;
}

// stage one 16B chunk into LDS. Builtin path: linear LDS write (wave-uniform
// base + lane*16; lane0's ptr is the base). Fallback: direct copy to same slot.
DEV void stage16(const unsigned short* g, unsigned short* l) {
#if __has_builtin(__builtin_amdgcn_global_load_lds)
  __builtin_amdgcn_global_load_lds((const __attribute__((address_space(1))) void*)g,
                                   (__attribute__((address_space(3))) void*)l, 16, 0, 0);
#else
  *(bf16x8*)l = *(const bf16x8*)g;
#endif
}

// ------------------------------------------------------- weight transpose/convert
// out[N][K] bf16 = in[K][N] f32
__global__ __launch_bounds__(256)
void tconv_k(const float* __restrict__ in, unsigned short* __restrict__ out, int K, int N)
{
  __shared__ float t[64][65];
  const int n0 = blockIdx.x * 64, k0 = blockIdx.y * 64;
  #pragma unroll
  for (int i = 0; i < 16; i++) {
    int idx = i * 256 + threadIdx.x;
    int r = idx >> 6, c = idx & 63;
    t[r][c] = in[(size_t)(k0 + r) * N + n0 + c];
  }
  __syncthreads();
  #pragma unroll
  for (int i = 0; i < 16; i++) {
    int idx = i * 256 + threadIdx.x;
    int rn = idx >> 6, ck = idx & 63;
    out[(size_t)(n0 + rn) * K + k0 + ck] = f2bf(t[ck][rn]);
  }
}

// ---------------------------------------------------------------- GEMM (m97-style)
// C[M,N] = A[M,K](bf16) @ Bt[N,K](bf16)^T + bias. 128x128 tile, BK=64, 4 waves,
// global_load_lds staging (linear LDS, source-permuted for XOR swizzle).
enum { EP_BF16 = 0, EP_GELU = 1, EP_RESID = 2, EP_F32 = 3 };

template<int MODE>
__global__ __launch_bounds__(256, 2)
void gemm2_k(const unsigned short* __restrict__ A, const unsigned short* __restrict__ Bt,
             const float* __restrict__ bias, void* __restrict__ out,
             float* __restrict__ xres, const float* __restrict__ gsh,
             const float* __restrict__ gpb, int N, int K)
{
  __shared__ unsigned short As[128 * 64];
  __shared__ unsigned short Bs[128 * 64];
  const int tid = threadIdx.x;
  const int lane = tid & 63, wv = tid >> 6;
  const int row0 = blockIdx.x * 128, col0 = blockIdx.y * 128;
  const int wm = (wv >> 1) * 64, wn = (wv & 1) * 64;

  f32x4 acc[4][4] = {};

  for (int k0 = 0; k0 < K; k0 += 64) {
    #pragma unroll
    for (int i = 0; i < 4; i++) {
      int ch = i * 256 + tid;
      int r = ch >> 3;
      int c8 = (ch & 7) ^ (r & 7);           // inverse swizzle on SOURCE
      stage16(A + (size_t)(row0 + r) * K + k0 + c8 * 8, As + ch * 8);
    }
    #pragma unroll
    for (int i = 0; i < 4; i++) {
      int ch = i * 256 + tid;
      int r = ch >> 3;
      int c8 = (ch & 7) ^ (r & 7);
      stage16(Bt + (size_t)(col0 + r) * K + k0 + c8 * 8, Bs + ch * 8);
    }
    __syncthreads();
    #pragma unroll
    for (int kk = 0; kk < 2; kk++) {
      bf16x8 af[4], bfr[4];
      const int bcol = kk * 64 + (lane >> 4) * 16;
      #pragma unroll
      for (int m = 0; m < 4; m++) {
        int r = wm + m * 16 + (lane & 15);
        af[m] = *(const bf16x8*)((char*)As + r * 128 + (bcol ^ ((r & 7) << 4)));
      }
      #pragma unroll
      for (int n = 0; n < 4; n++) {
        int r = wn + n * 16 + (lane & 15);
        bfr[n] = *(const bf16x8*)((char*)Bs + r * 128 + (bcol ^ ((r & 7) << 4)));
      }
      #pragma unroll
      for (int m = 0; m < 4; m++)
        #pragma unroll
        for (int n = 0; n < 4; n++)
          acc[m][n] = __builtin_amdgcn_mfma_f32_16x16x32_bf16(af[m], bfr[n], acc[m][n], 0, 0, 0);
    }
    __syncthreads();
  }

  const int rbase = row0 + wm + ((lane >> 4) << 2);
  const int cbase = col0 + wn + (lane & 15);
  #pragma unroll
  for (int n = 0; n < 4; n++) {
    int gcol = cbase + n * 16;
    float bv = bias[gcol];
    #pragma unroll
    for (int m = 0; m < 4; m++) {
      #pragma unroll
      for (int r = 0; r < 4; r++) {
        int grow = rbase + m * 16 + r;
        float v = acc[m][n][r] + bv;
        if constexpr (MODE == EP_BF16) {
          ((unsigned short*)out)[(size_t)grow * N + gcol] = f2bf(v);
        } else if constexpr (MODE == EP_GELU) {
          float g = 0.5f * v * (1.f + erff(v * 0.70710678118654752f));
          ((unsigned short*)out)[(size_t)grow * N + gcol] = f2bf(g);
        } else if constexpr (MODE == EP_RESID) {
          int b = grow / Lz;
          float g = gsh[gcol] + gpb[(size_t)b * 6144 + gcol];
          xres[(size_t)grow * Cz + gcol] += g * v;
        } else {
          ((float*)out)[(size_t)grow * N + gcol] = v;
        }
      }
    }
  }
}

// ---------------------------------------------------------------- LayerNorm (+adaLN) -> bf16
__global__ __launch_bounds__(256)
void ln_k(const float* __restrict__ x, unsigned short* __restrict__ out,
          const float* __restrict__ ssh, const float* __restrict__ spb, int sstride,
          const float* __restrict__ hsh, const float* __restrict__ hpb, int hstride)
{
  const int row = blockIdx.x, tid = threadIdx.x;
  const int b = row / Lz;
  const float* xr = x + (size_t)row * Cz;
  float v[4];
  float s = 0.f;
  #pragma unroll
  for (int i = 0; i < 4; i++) { v[i] = xr[tid + i * 256]; s += v[i]; }
  __shared__ float red[8];
  #pragma unroll
  for (int o = 32; o > 0; o >>= 1) s += __shfl_xor(s, o, 64);
  if ((tid & 63) == 0) red[tid >> 6] = s;
  __syncthreads();
  float mean = (red[0] + red[1] + red[2] + red[3]) * (1.f / 1024.f);
  float vs = 0.f;
  #pragma unroll
  for (int i = 0; i < 4; i++) { float d = v[i] - mean; vs += d * d; }
  #pragma unroll
  for (int o = 32; o > 0; o >>= 1) vs += __shfl_xor(vs, o, 64);
  __syncthreads();
  if ((tid & 63) == 0) red[4 + (tid >> 6)] = vs;
  __syncthreads();
  float var = (red[4] + red[5] + red[6] + red[7]) * (1.f / 1024.f);
  float rstd = rsqrtf(var + 1e-6f);
  #pragma unroll
  for (int i = 0; i < 4; i++) {
    int c = tid + i * 256;
    float sc = (ssh ? ssh[c] : 0.f) + spb[(size_t)b * sstride + c];
    float sh = (hsh ? hsh[c] : 0.f) + hpb[(size_t)b * hstride + c];
    out[(size_t)row * Cz + c] = f2bf((v[i] - mean) * rstd * (1.f + sc) + sh);
  }
}

// ---------------------------------------------------------------- attention v2
// grid (bh=512, qc=4). 8 waves/block; wave w owns q rows [qc*128+w*16, +16).
// S^T = mfma(K, Q): lane holds S^T[k=c*16+4g+r][q=lane&15], g=lane>>4.
// Exact online softmax (level-prefix mask), scalar PV (lane: 4 k x 64 d),
// cross-group shuffle-sum of O at the end.
__global__ __launch_bounds__(512)
void attn2_k(const unsigned short* __restrict__ qb,
             const unsigned short* __restrict__ kvb,
             unsigned short* __restrict__ ob)
{
  __shared__ unsigned short Ks[25 * 16 * 64];  // swizzled rows
  __shared__ unsigned short Vs[25 * 16 * 64];  // linear rows
  const int bh = blockIdx.x, b = bh >> 4, h = bh & 15;
  const int qc = blockIdx.y;
  const int tid = threadIdx.x;
  const int q0 = qc * 128;
  const int qlast = min(q0 + 127, 399);
  const int nch = (row_kmax(qlast) + 15) >> 4;

  const size_t kvbase = ((size_t)b * Lz) * 2048 + h * 64;
  for (int c16 = tid; c16 < nch * 128; c16 += 512) {
    int l = c16 >> 3, d8 = c16 & 7;
    bf16x8 kv_ = *(const bf16x8*)&kvb[kvbase + (size_t)l * 2048 + d8 * 8];
    *(bf16x8*)((char*)Ks + l * 128 + ((d8 * 16) ^ ((l & 7) << 4))) = kv_;
    bf16x8 vv = *(const bf16x8*)&kvb[kvbase + (size_t)l * 2048 + 1024 + d8 * 8];
    *(bf16x8*)((char*)Vs + l * 128 + d8 * 16) = vv;
  }
  __syncthreads();

  const int wv = tid >> 6, lane = tid & 63, g = lane >> 4;
  const int qw0 = q0 + wv * 16;
  if (qw0 >= Lz) return;                   // no barriers after this point
  const int qrow = qw0 + (lane & 15);
  const int my_kmax = row_kmax(qrow);
  const int nch_w = (row_kmax(qw0 + 15) + 15) >> 4;

  const unsigned short* qp = qb + (size_t)(b * Lz + qrow) * Cz + h * 64;
  bf16x8 qf0 = *(const bf16x8*)(qp + g * 8);
  bf16x8 qf1 = *(const bf16x8*)(qp + 32 + g * 8);

  float m = -1e30f, lsum = 0.f;
  float oacc[64];
  #pragma unroll
  for (int d = 0; d < 64; d++) oacc[d] = 0.f;

  for (int c = 0; c < nch_w; ++c) {
    const int kr = c * 16 + (lane & 15);
    const char* kbase = (const char*)Ks + kr * 128;
    bf16x8 kf0 = *(const bf16x8*)(kbase + ((g * 16) ^ ((kr & 7) << 4)));
    bf16x8 kf1 = *(const bf16x8*)(kbase + ((64 + g * 16) ^ ((kr & 7) << 4)));
    f32x4 st = {0.f, 0.f, 0.f, 0.f};
    st = __builtin_amdgcn_mfma_f32_16x16x32_bf16(kf0, qf0, st, 0, 0, 0);
    st = __builtin_amdgcn_mfma_f32_16x16x32_bf16(kf1, qf1, st, 0, 0, 0);

    float s[4]; float cmax = -1e30f;
    #pragma unroll
    for (int r = 0; r < 4; r++) {
      int kg = c * 16 + 4 * g + r;
      s[r] = (kg < my_kmax) ? st[r] * 0.125f : -1e30f;
      cmax = fmaxf(cmax, s[r]);
    }
    cmax = fmaxf(cmax, __shfl_xor(cmax, 16, 64));
    cmax = fmaxf(cmax, __shfl_xor(cmax, 32, 64));
    float mnew = fmaxf(m, cmax);
    float f = __expf(m - mnew);
    float p[4], ps = 0.f;
    #pragma unroll
    for (int r = 0; r < 4; r++) { p[r] = __expf(s[r] - mnew); ps += p[r]; }
    ps += __shfl_xor(ps, 16, 64);
    ps += __shfl_xor(ps, 32, 64);
    lsum = lsum * f + ps;
    m = mnew;
    #pragma unroll
    for (int d = 0; d < 64; d++) oacc[d] *= f;

    // PV: lane's 4 k rows (k = c*16 + 4g + r) x all 64 d (broadcast LDS reads)
    #pragma unroll
    for (int r = 0; r < 4; r++) {
      const unsigned short* vrow = (const unsigned short*)((const char*)Vs + (c * 16 + 4 * g + r) * 128);
      float pv = p[r];
      #pragma unroll
      for (int dd = 0; dd < 8; dd++) {
        bf16x8 vv = *(const bf16x8*)(vrow + dd * 8);
        #pragma unroll
        for (int j = 0; j < 8; j++)
          oacc[dd * 8 + j] += pv * bf2f((unsigned short)vv[j]);
      }
    }
  }

  #pragma unroll
  for (int d = 0; d < 64; d++) {
    oacc[d] += __shfl_xor(oacc[d], 16, 64);
    oacc[d] += __shfl_xor(oacc[d], 32, 64);
  }
  if (g == 0) {
    float inv = 1.f / lsum;
    unsigned short* op = ob + (size_t)(b * Lz + qrow) * Cz + h * 64;
    #pragma unroll
    for (int d = 0; d < 64; d++) op[d] = f2bf(oacc[d] * inv);
  }
}

// ---------------------------------------------------------------- preamble
__global__ __launch_bounds__(256)
void cond_k(const float* __restrict__ pc, const float* __restrict__ pw,
            const float* __restrict__ pb, float* __restrict__ cond,
            float* __restrict__ silu)
{
  const int b = blockIdx.y;
  const int n = blockIdx.x * 256 + threadIdx.x;
  __shared__ float a[256];
  a[threadIdx.x] = pc[b * 256 + threadIdx.x];
  __syncthreads();
  float s = pb[n];
  for (int k = 0; k < 256; k++) s += a[k] * pw[(size_t)k * Cz + n];
  cond[(size_t)b * Cz + n] = s;
  silu[(size_t)b * Cz + n] = s / (1.f + __expf(-s));
}

__global__ __launch_bounds__(256)
void smallmm_k(const float* __restrict__ A, const float* __restrict__ W,
               const float* __restrict__ bias, float* __restrict__ out, int N)
{
  const int b = blockIdx.y;
  const int n = blockIdx.x * 256 + threadIdx.x;
  __shared__ float a[1024];
  for (int i = threadIdx.x; i < 1024; i += 256) a[i] = A[(size_t)b * 1024 + i];
  __syncthreads();
  float s = bias[n];
  for (int k = 0; k < 1024; k++) s += a[k] * W[(size_t)k * N + n];
  out[(size_t)b * N + n] = s;
}

template<int MODE>
__global__ __launch_bounds__(256)
void embed_k(const float* __restrict__ src, const float* __restrict__ ww,
             const float* __restrict__ wb, const float* __restrict__ cond,
             const float* __restrict__ pos_start, const float* __restrict__ pos1,
             const float* __restrict__ ltab, void* __restrict__ out)
{
  const int r0 = blockIdx.x * 4;
  const int tid = threadIdx.x;
  const int b = r0 / Lz;
  __shared__ float a[4][64];
  {
    int rr = tid >> 6, k = tid & 63;
    int l = (r0 + rr) % Lz;
    float val;
    if (MODE == 0) val = (l == 0) ? 0.f : src[((size_t)b * (Lz - 1) + (l - 1)) * 64 + k];
    else           val = src[((size_t)(r0 + rr)) * 64 + k];
    a[rr][k] = val;
  }
  __syncthreads();
  #pragma unroll
  for (int ci = 0; ci < 4; ci++) {
    int c = tid + ci * 256;
    float s[4];
    #pragma unroll
    for (int rr = 0; rr < 4; rr++) {
      int l = (r0 + rr) % Lz;
      s[rr] = wb[c] + ltab[(size_t)level_of(l) * Cz + c] + pos1[(size_t)l * Cz + c];
    }
    for (int k = 0; k < 64; k++) {
      float w = ww[(size_t)k * Cz + c];
      #pragma unroll
      for (int rr = 0; rr < 4; rr++) s[rr] += a[rr][k] * w;
    }
    #pragma unroll
    for (int rr = 0; rr < 4; rr++) {
      int l = (r0 + rr) % Lz;
      if (MODE == 0) {
        float val = s[rr];
        if (l == 0) val = cond[(size_t)b * Cz + c] + pos_start[c] + ltab[c] + pos1[c];
        ((float*)out)[((size_t)(r0 + rr)) * Cz + c] = val;
      } else {
        ((unsigned short*)out)[((size_t)(r0 + rr)) * Cz + c] = f2bf(s[rr]);
      }
    }
  }
}

// ---------------------------------------------------------------- launch
extern "C" void kernel_launch(void* const* d_in, const int* in_sizes, int n_in,
                              void* d_out, int out_size, void* d_ws, size_t ws_size,
                              hipStream_t stream)
{
  (void)in_sizes; (void)n_in; (void)out_size; (void)ws_size;
  const float* x_blcv   = (const float*)d_in[0];
  const float* poc_ctx  = (const float*)d_in[1];
  const float* poc_cond = (const float*)d_in[2];
  const float* word_w   = (const float*)d_in[3];
  const float* word_b   = (const float*)d_in[4];
  const float* poc_w    = (const float*)d_in[5];
  const float* poc_b    = (const float*)d_in[6];
  const float* pos_start= (const float*)d_in[7];
  const float* pos_1lc  = (const float*)d_in[8];
  const float* lvl_tab  = (const float*)d_in[9];
  const float* ada_w    = (const float*)d_in[10];
  const float* ada_b    = (const float*)d_in[11];
  const float* ada_gss  = (const float*)d_in[12];
  const float* q_w      = (const float*)d_in[13];
  const float* q_b      = (const float*)d_in[14];
  const float* kv_w     = (const float*)d_in[15];
  const float* kv_b     = (const float*)d_in[16];
  const float* proj_w   = (const float*)d_in[17];
  const float* proj_b   = (const float*)d_in[18];
  const float* fc1_w    = (const float*)d_in[19];
  const float* fc1_b    = (const float*)d_in[20];
  const float* fc2_w    = (const float*)d_in[21];
  const float* fc2_b    = (const float*)d_in[22];
  const float* head_ada_w = (const float*)d_in[23];
  const float* head_ada_b = (const float*)d_in[24];
  const float* head_w   = (const float*)d_in[25];
  const float* head_b   = (const float*)d_in[26];

  char* p = (char*)d_ws;
  auto carve = [&](size_t bytes) { void* r = (void*)p; p += (bytes + 255) & ~(size_t)255; return r; };
  float* x            = (float*)carve((size_t)BL * Cz * 4);
  unsigned short* xn  = (unsigned short*)carve((size_t)BL * Cz * 2);
  unsigned short* poc = (unsigned short*)carve((size_t)BL * Cz * 2);
  unsigned short* qbf = (unsigned short*)carve((size_t)BL * Cz * 2);
  unsigned short* kvb = (unsigned short*)carve((size_t)BL * 2 * Cz * 2);
  unsigned short* ob  = (unsigned short*)carve((size_t)BL * Cz * 2);
  unsigned short* hdn = (unsigned short*)carve((size_t)BL * MLPz * 2);
  unsigned short* wt  = (unsigned short*)carve((size_t)12582912 * 2);  // per-depth bf16 W^T slab
  float* cond  = (float*)carve(32 * 1024 * 4);
  float* siluc = (float*)carve(32 * 1024 * 4);
  float* gss   = (float*)carve(32 * 6144 * 4);
  float* ss    = (float*)carve(32 * 2048 * 4);

  unsigned short* qwt  = wt;
  unsigned short* kvwt = wt + 1048576;
  unsigned short* pjwt = wt + 3145728;
  unsigned short* f1wt = wt + 4194304;
  unsigned short* f2wt = wt + 8388608;

  cond_k<<<dim3(4, 32), 256, 0, stream>>>(poc_cond, poc_w, poc_b, cond, siluc);
  smallmm_k<<<dim3(24, 32), 256, 0, stream>>>(siluc, ada_w, ada_b, gss, 6144);
  smallmm_k<<<dim3(8, 32), 256, 0, stream>>>(siluc, head_ada_w, head_ada_b, ss, 2048);
  embed_k<0><<<3200, 256, 0, stream>>>(x_blcv, word_w, word_b, cond, pos_start, pos_1lc, lvl_tab, x);
  embed_k<1><<<3200, 256, 0, stream>>>(poc_ctx, word_w, word_b, cond, pos_start, pos_1lc, lvl_tab, poc);

  for (int d = 0; d < 8; d++) {
    const float* ag = ada_gss + (size_t)d * 6144;
    tconv_k<<<dim3(16, 16), 256, 0, stream>>>(q_w + (size_t)d * 1048576, qwt, 1024, 1024);
    tconv_k<<<dim3(32, 16), 256, 0, stream>>>(kv_w + (size_t)d * 2097152, kvwt, 1024, 2048);
    tconv_k<<<dim3(16, 16), 256, 0, stream>>>(proj_w + (size_t)d * 1048576, pjwt, 1024, 1024);
    tconv_k<<<dim3(64, 16), 256, 0, stream>>>(fc1_w + (size_t)d * 4194304, f1wt, 1024, 4096);
    tconv_k<<<dim3(16, 64), 256, 0, stream>>>(fc2_w + (size_t)d * 4194304, f2wt, 4096, 1024);

    ln_k<<<BL, 256, 0, stream>>>(x, xn, ag + 2 * 1024, gss + 2 * 1024, 6144,
                                 ag + 4 * 1024, gss + 4 * 1024, 6144);
    gemm2_k<EP_BF16><<<dim3(100, 8), 256, 0, stream>>>(
        xn, qwt, q_b + d * 1024, qbf, nullptr, nullptr, nullptr, 1024, 1024);
    gemm2_k<EP_BF16><<<dim3(100, 16), 256, 0, stream>>>(
        poc, kvwt, kv_b + d * 2048, kvb, nullptr, nullptr, nullptr, 2048, 1024);
    attn2_k<<<dim3(512, 4), 512, 0, stream>>>(qbf, kvb, ob);
    gemm2_k<EP_RESID><<<dim3(100, 8), 256, 0, stream>>>(
        ob, pjwt, proj_b + d * 1024, nullptr, x, ag + 0, gss + 0, 1024, 1024);
    ln_k<<<BL, 256, 0, stream>>>(x, xn, ag + 3 * 1024, gss + 3 * 1024, 6144,
                                 ag + 5 * 1024, gss + 5 * 1024, 6144);
    gemm2_k<EP_GELU><<<dim3(100, 32), 256, 0, stream>>>(
        xn, f1wt, fc1_b + d * 4096, hdn, nullptr, nullptr, nullptr, 4096, 1024);
    gemm2_k<EP_RESID><<<dim3(100, 8), 256, 0, stream>>>(
        hdn, f2wt, fc2_b + d * 1024, nullptr, x, ag + 1024, gss + 1024, 1024, 4096);
  }
  ln_k<<<BL, 256, 0, stream>>>(x, xn, nullptr, ss, 2048, nullptr, ss + 1024, 2048);
  tconv_k<<<dim3(64, 16), 256, 0, stream>>>(head_w, wt, 1024, 4096);
  gemm2_k<EP_F32><<<dim3(100, 32), 256, 0, stream>>>(
      xn, wt, head_b, d_out, nullptr, nullptr, nullptr, 4096, 1024);
}

// Round 3
// 6115.062 us; speedup vs baseline: 3.9029x; 1.2834x over previous
//
#include <hip/hip_runtime.h>
#include <hip/hip_bf16.h>
#include <math.h>

#define DEV __device__ __forceinline__

typedef __attribute__((ext_vector_type(4))) float f32x4;
typedef __attribute__((ext_vector_type(8))) short bf16x8;
typedef __attribute__((ext_vector_type(4))) short s16x4;

static constexpr int Bz = 32, Lz = 400, Cz = 1024, MLPz = 4096;
static constexpr int BL = Bz * Lz;  // 12800

DEV float bf2f(unsigned short u) {
  union { unsigned int i; float f; } v; v.i = ((unsigned int)u) << 16; return v.f;
}
DEV unsigned short f2bf(float f) {
  union { float f; unsigned int i; } v; v.f = f;
  unsigned int r = v.i + 0x7FFFu + ((v.i >> 16) & 1u);
  return (unsigned short)(r >> 16);
}

DEV int level_of(int l) {
  const int cum[13] = {1,3,6,10,16,25,38,57,84,124,184,272,400};
  int lv = 12;
  #pragma unroll
  for (int i = 12; i >= 0; i--) if (l < cum[i]) lv = i;
  return lv;
}
DEV int row_kmax(int l) {
  const int cum[13] = {1,3,6,10,16,25,38,57,84,124,184,272,400};
  int km = 400;
  #pragma unroll
  for (int i = 12; i >= 0; i--) if (l < cum[i]) km = cum[i];
  return km;
}

DEV void stage16(const unsigned short* g, unsigned short* l) {
#if __has_builtin(__builtin_amdgcn_global_load_lds)
  __builtin_amdgcn_global_load_lds((const __attribute__((address_space(1))) void*)g,
                                   (__attribute__((address_space(3))) void*)l, 16, 0, 0);
#else
  *(bf16x8*)l = *(const bf16x8*)g;
#endif
}

// ------------------------------------------------------- weight transpose/convert
__global__ __launch_bounds__(256)
void tconv_k(const float* __restrict__ in, unsigned short* __restrict__ out, int K, int N)
{
  __shared__ float t[64][65];
  const int n0 = blockIdx.x * 64, k0 = blockIdx.y * 64;
  #pragma unroll
  for (int i = 0; i < 16; i++) {
    int idx = i * 256 + threadIdx.x;
    int r = idx >> 6, c = idx & 63;
    t[r][c] = in[(size_t)(k0 + r) * N + n0 + c];
  }
  __syncthreads();
  #pragma unroll
  for (int i = 0; i < 16; i++) {
    int idx = i * 256 + threadIdx.x;
    int rn = idx >> 6, ck = idx & 63;
    out[(size_t)(n0 + rn) * K + k0 + ck] = f2bf(t[ck][rn]);
  }
}

// ---------------------------------------------------------------- GEMM (m97-style)
enum { EP_BF16 = 0, EP_GELU = 1, EP_RESID = 2, EP_F32 = 3, EP_KV = 4 };

template<int MODE>
__global__ __launch_bounds__(256, 2)
void gemm2_k(const unsigned short* __restrict__ A, const unsigned short* __restrict__ Bt,
             const float* __restrict__ bias, void* __restrict__ out,
             float* __restrict__ xres, const float* __restrict__ gsh,
             const float* __restrict__ gpb, unsigned short* __restrict__ vtb,
             int N, int K)
{
  __shared__ unsigned short As[128 * 64];
  __shared__ unsigned short Bs[128 * 64];
  const int tid = threadIdx.x;
  const int lane = tid & 63, wv = tid >> 6;
  const int row0 = blockIdx.x * 128, col0 = blockIdx.y * 128;
  const int wm = (wv >> 1) * 64, wn = (wv & 1) * 64;

  f32x4 acc[4][4] = {};

  for (int k0 = 0; k0 < K; k0 += 64) {
    #pragma unroll
    for (int i = 0; i < 4; i++) {
      int ch = i * 256 + tid;
      int r = ch >> 3;
      int c8 = (ch & 7) ^ (r & 7);
      stage16(A + (size_t)(row0 + r) * K + k0 + c8 * 8, As + ch * 8);
    }
    #pragma unroll
    for (int i = 0; i < 4; i++) {
      int ch = i * 256 + tid;
      int r = ch >> 3;
      int c8 = (ch & 7) ^ (r & 7);
      stage16(Bt + (size_t)(col0 + r) * K + k0 + c8 * 8, Bs + ch * 8);
    }
    __syncthreads();
    #pragma unroll
    for (int kk = 0; kk < 2; kk++) {
      bf16x8 af[4], bfr[4];
      const int bcol = kk * 64 + (lane >> 4) * 16;
      #pragma unroll
      for (int m = 0; m < 4; m++) {
        int r = wm + m * 16 + (lane & 15);
        af[m] = *(const bf16x8*)((char*)As + r * 128 + (bcol ^ ((r & 7) << 4)));
      }
      #pragma unroll
      for (int n = 0; n < 4; n++) {
        int r = wn + n * 16 + (lane & 15);
        bfr[n] = *(const bf16x8*)((char*)Bs + r * 128 + (bcol ^ ((r & 7) << 4)));
      }
      #pragma unroll
      for (int m = 0; m < 4; m++)
        #pragma unroll
        for (int n = 0; n < 4; n++)
          acc[m][n] = __builtin_amdgcn_mfma_f32_16x16x32_bf16(af[m], bfr[n], acc[m][n], 0, 0, 0);
    }
    __syncthreads();
  }

  const int rbase = row0 + wm + ((lane >> 4) << 2);
  const int cbase = col0 + wn + (lane & 15);
  #pragma unroll
  for (int n = 0; n < 4; n++) {
    int gcol = cbase + n * 16;
    float bv = bias[gcol];
    #pragma unroll
    for (int m = 0; m < 4; m++) {
      #pragma unroll
      for (int r = 0; r < 4; r++) {
        int grow = rbase + m * 16 + r;
        float v = acc[m][n][r] + bv;
        if constexpr (MODE == EP_BF16) {
          ((unsigned short*)out)[(size_t)grow * N + gcol] = f2bf(v);
        } else if constexpr (MODE == EP_GELU) {
          float g = 0.5f * v * (1.f + erff(v * 0.70710678118654752f));
          ((unsigned short*)out)[(size_t)grow * N + gcol] = f2bf(g);
        } else if constexpr (MODE == EP_RESID) {
          int b = grow / Lz;
          float g = gsh[gcol] + gpb[(size_t)b * 6144 + gcol];
          xres[(size_t)grow * Cz + gcol] += g * v;
        } else if constexpr (MODE == EP_KV) {
          if (gcol < 1024) {
            ((unsigned short*)out)[(size_t)grow * 1024 + gcol] = f2bf(v);  // K row-major
          } else {
            int b = grow / Lz, l = grow - b * Lz;
            int h = (gcol >> 6) & 15, d = gcol & 63;
            vtb[(((size_t)b * 16 + h) * 64 + d) * Lz + l] = f2bf(v);      // V transposed
          }
        } else {
          ((float*)out)[(size_t)grow * N + gcol] = v;
        }
      }
    }
  }
}

// ---------------------------------------------------------------- LayerNorm (+adaLN) -> bf16
__global__ __launch_bounds__(256)
void ln_k(const float* __restrict__ x, unsigned short* __restrict__ out,
          const float* __restrict__ ssh, const float* __restrict__ spb, int sstride,
          const float* __restrict__ hsh, const float* __restrict__ hpb, int hstride)
{
  const int row = blockIdx.x, tid = threadIdx.x;
  const int b = row / Lz;
  const float* xr = x + (size_t)row * Cz;
  float v[4];
  float s = 0.f;
  #pragma unroll
  for (int i = 0; i < 4; i++) { v[i] = xr[tid + i * 256]; s += v[i]; }
  __shared__ float red[8];
  #pragma unroll
  for (int o = 32; o > 0; o >>= 1) s += __shfl_xor(s, o, 64);
  if ((tid & 63) == 0) red[tid >> 6] = s;
  __syncthreads();
  float mean = (red[0] + red[1] + red[2] + red[3]) * (1.f / 1024.f);
  float vs = 0.f;
  #pragma unroll
  for (int i = 0; i < 4; i++) { float d = v[i] - mean; vs += d * d; }
  #pragma unroll
  for (int o = 32; o > 0; o >>= 1) vs += __shfl_xor(vs, o, 64);
  __syncthreads();
  if ((tid & 63) == 0) red[4 + (tid >> 6)] = vs;
  __syncthreads();
  float var = (red[4] + red[5] + red[6] + red[7]) * (1.f / 1024.f);
  float rstd = rsqrtf(var + 1e-6f);
  #pragma unroll
  for (int i = 0; i < 4; i++) {
    int c = tid + i * 256;
    float sc = (ssh ? ssh[c] : 0.f) + spb[(size_t)b * sstride + c];
    float sh = (hsh ? hsh[c] : 0.f) + hpb[(size_t)b * hstride + c];
    out[(size_t)row * Cz + c] = f2bf((v[i] - mean) * rstd * (1.f + sc) + sh);
  }
}

// ---------------------------------------------------------------- attention v3 (MFMA PV)
// grid (bh=512, qc=4), 8 waves. Wave w: q rows [qc*128+16w, +16).
// QK^T: S^T = mfma(K,Q) -> lane holds S^T[k=32sc+16cp+4g+r][q=lane&15].
// Softmax over 32-k superchunk, P^T -> bf16 via per-wave swizzled LDS buffer,
// PV: O^T[d][q] = mfma(V^T frag, P^T frag) per 16-d block.
__global__ __launch_bounds__(512)
void attn3_k(const unsigned short* __restrict__ qb,
             const unsigned short* __restrict__ kbuf,
             const unsigned short* __restrict__ vtb,
             unsigned short* __restrict__ ob)
{
  __shared__ unsigned short Ks[400 * 64];     // swizzled rows, 128 B/row
  __shared__ unsigned short Vt[64 * 408];     // V^T, pitch 816 B
  __shared__ unsigned short Pl[8][512];       // per-wave P buffer (16q x 32k bf16)
  const int bh = blockIdx.x, b = bh >> 4, h = bh & 15;
  const int qc = blockIdx.y;
  const int tid = threadIdx.x;
  const int q0 = qc * 128;
  const int nch = (row_kmax(min(q0 + 127, Lz - 1)) + 15) >> 4;

  // stage K (XOR-swizzled rows)
  const size_t kbase = (size_t)b * Lz * 1024 + h * 64;
  for (int i = tid; i < nch * 128; i += 512) {
    int l = i >> 3, d8 = i & 7;
    bf16x8 kr = *(const bf16x8*)&kbuf[kbase + (size_t)l * 1024 + d8 * 8];
    *(bf16x8*)((char*)Ks + l * 128 + ((d8 * 16) ^ ((l & 7) << 4))) = kr;
  }
  // stage V^T (full 400 k, 50 x 16B chunks per d-row)
  const size_t vbase = ((size_t)b * 16 + h) * 64 * Lz;
  for (int i = tid; i < 64 * 50; i += 512) {
    int d = i / 50, c8 = i - d * 50;
    *(bf16x8*)((char*)Vt + d * 816 + c8 * 16) = *(const bf16x8*)&vtb[vbase + (size_t)d * Lz + c8 * 8];
  }
  __syncthreads();

  const int wv = tid >> 6, lane = tid & 63, g = lane >> 4, q = lane & 15;
  const int qw0 = q0 + wv * 16;
  if (qw0 >= Lz) return;                      // no barriers below
  const int qrow = qw0 + q;
  const int my_kmax = row_kmax(qrow);
  const int nsch = (row_kmax(qw0 + 15) + 31) >> 5;

  const unsigned short* qp = qb + (size_t)(b * Lz + qrow) * Cz + h * 64;
  bf16x8 qf0 = *(const bf16x8*)(qp + g * 8);
  bf16x8 qf1 = *(const bf16x8*)(qp + 32 + g * 8);
  unsigned short* myP = &Pl[wv][0];

  float m = -1e30f, lsum = 0.f;
  f32x4 acc[4] = {};

  for (int sc = 0; sc < nsch; ++sc) {
    f32x4 st0 = {0.f,0.f,0.f,0.f}, st1 = {0.f,0.f,0.f,0.f};
    {
      int kr = sc * 32 + q;
      const char* kb = (const char*)Ks + kr * 128;
      int sw = (kr & 7) << 4;
      bf16x8 k0 = *(const bf16x8*)(kb + ((g * 16) ^ sw));
      bf16x8 k1 = *(const bf16x8*)(kb + ((64 + g * 16) ^ sw));
      st0 = __builtin_amdgcn_mfma_f32_16x16x32_bf16(k0, qf0, st0, 0, 0, 0);
      st0 = __builtin_amdgcn_mfma_f32_16x16x32_bf16(k1, qf1, st0, 0, 0, 0);
    }
    {
      int kr = sc * 32 + 16 + q;
      const char* kb = (const char*)Ks + kr * 128;
      int sw = (kr & 7) << 4;
      bf16x8 k0 = *(const bf16x8*)(kb + ((g * 16) ^ sw));
      bf16x8 k1 = *(const bf16x8*)(kb + ((64 + g * 16) ^ sw));
      st1 = __builtin_amdgcn_mfma_f32_16x16x32_bf16(k0, qf0, st1, 0, 0, 0);
      st1 = __builtin_amdgcn_mfma_f32_16x16x32_bf16(k1, qf1, st1, 0, 0, 0);
    }

    // masked scores for 8 k's, superchunk max
    float s8[8]; float cmax = -1e30f;
    #pragma unroll
    for (int r = 0; r < 4; r++) {
      int k0g = sc * 32 + 4 * g + r;
      int k1g = k0g + 16;
      s8[r]     = (k0g < my_kmax) ? st0[r] * 0.125f : -1e30f;
      s8[4 + r] = (k1g < my_kmax) ? st1[r] * 0.125f : -1e30f;
      cmax = fmaxf(cmax, fmaxf(s8[r], s8[4 + r]));
    }
    cmax = fmaxf(cmax, __shfl_xor(cmax, 16, 64));
    cmax = fmaxf(cmax, __shfl_xor(cmax, 32, 64));
    float mnew = fmaxf(m, cmax);
    float f = __expf(m - mnew);
    float p[8], ps = 0.f;
    #pragma unroll
    for (int r = 0; r < 8; r++) { p[r] = __expf(s8[r] - mnew); ps += p[r]; }
    ps += __shfl_xor(ps, 16, 64);
    ps += __shfl_xor(ps, 32, 64);
    lsum = lsum * f + ps;
    m = mnew;
    #pragma unroll
    for (int blk = 0; blk < 4; blk++)
      #pragma unroll
      for (int j = 0; j < 4; j++) acc[blk][j] *= f;

    // write P^T (bf16) to per-wave swizzled buffer: row q, u32-granule w^q
    #pragma unroll
    for (int cp = 0; cp < 2; cp++) {
      #pragma unroll
      for (int j = 0; j < 2; j++) {
        unsigned int lo = f2bf(p[4 * cp + 2 * j]);
        unsigned int hi = f2bf(p[4 * cp + 2 * j + 1]);
        int w = 8 * cp + 2 * g + j;
        *(unsigned int*)((char*)myP + q * 64 + 4 * (w ^ q)) = lo | (hi << 16);
      }
    }

    // B-fragment: k = 8g..8g+8 at col q -> granules (4g+i)^q
    unsigned int pw[4];
    #pragma unroll
    for (int i = 0; i < 4; i++)
      pw[i] = *(const unsigned int*)((const char*)myP + q * 64 + 4 * ((4 * g + i) ^ q));
    bf16x8 pfrag;
    #pragma unroll
    for (int i = 0; i < 4; i++) {
      pfrag[2 * i]     = (short)(pw[i] & 0xFFFF);
      pfrag[2 * i + 1] = (short)(pw[i] >> 16);
    }

    // PV: 4 d-blocks
    #pragma unroll
    for (int blk = 0; blk < 4; blk++) {
      bf16x8 vf = *(const bf16x8*)((const char*)Vt + (16 * blk + q) * 816 + (sc * 32 + 8 * g) * 2);
      acc[blk] = __builtin_amdgcn_mfma_f32_16x16x32_bf16(vf, pfrag, acc[blk], 0, 0, 0);
    }
  }

  float inv = 1.f / lsum;
  unsigned short* op = ob + (size_t)(b * Lz + qrow) * Cz + h * 64;
  #pragma unroll
  for (int blk = 0; blk < 4; blk++)
    #pragma unroll
    for (int r = 0; r < 4; r++)
      op[16 * blk + 4 * g + r] = f2bf(acc[blk][r] * inv);
}

// ---------------------------------------------------------------- preamble
__global__ __launch_bounds__(256)
void cond_k(const float* __restrict__ pc, const float* __restrict__ pw,
            const float* __restrict__ pb, float* __restrict__ cond,
            float* __restrict__ silu)
{
  const int b = blockIdx.y;
  const int n = blockIdx.x * 256 + threadIdx.x;
  __shared__ float a[256];
  a[threadIdx.x] = pc[b * 256 + threadIdx.x];
  __syncthreads();
  float s = pb[n];
  for (int k = 0; k < 256; k++) s += a[k] * pw[(size_t)k * Cz + n];
  cond[(size_t)b * Cz + n] = s;
  silu[(size_t)b * Cz + n] = s / (1.f + __expf(-s));
}

__global__ __launch_bounds__(256)
void smallmm_k(const float* __restrict__ A, const float* __restrict__ W,
               const float* __restrict__ bias, float* __restrict__ out, int N)
{
  const int b = blockIdx.y;
  const int n = blockIdx.x * 256 + threadIdx.x;
  __shared__ float a[1024];
  for (int i = threadIdx.x; i < 1024; i += 256) a[i] = A[(size_t)b * 1024 + i];
  __syncthreads();
  float s = bias[n];
  for (int k = 0; k < 1024; k++) s += a[k] * W[(size_t)k * N + n];
  out[(size_t)b * N + n] = s;
}

template<int MODE>
__global__ __launch_bounds__(256)
void embed_k(const float* __restrict__ src, const float* __restrict__ ww,
             const float* __restrict__ wb, const float* __restrict__ cond,
             const float* __restrict__ pos_start, const float* __restrict__ pos1,
             const float* __restrict__ ltab, void* __restrict__ out)
{
  const int r0 = blockIdx.x * 4;
  const int tid = threadIdx.x;
  const int b = r0 / Lz;
  __shared__ float a[4][64];
  {
    int rr = tid >> 6, k = tid & 63;
    int l = (r0 + rr) % Lz;
    float val;
    if (MODE == 0) val = (l == 0) ? 0.f : src[((size_t)b * (Lz - 1) + (l - 1)) * 64 + k];
    else           val = src[((size_t)(r0 + rr)) * 64 + k];
    a[rr][k] = val;
  }
  __syncthreads();
  #pragma unroll
  for (int ci = 0; ci < 4; ci++) {
    int c = tid + ci * 256;
    float s[4];
    #pragma unroll
    for (int rr = 0; rr < 4; rr++) {
      int l = (r0 + rr) % Lz;
      s[rr] = wb[c] + ltab[(size_t)level_of(l) * Cz + c] + pos1[(size_t)l * Cz + c];
    }
    for (int k = 0; k < 64; k++) {
      float w = ww[(size_t)k * Cz + c];
      #pragma unroll
      for (int rr = 0; rr < 4; rr++) s[rr] += a[rr][k] * w;
    }
    #pragma unroll
    for (int rr = 0; rr < 4; rr++) {
      int l = (r0 + rr) % Lz;
      if (MODE == 0) {
        float val = s[rr];
        if (l == 0) val = cond[(size_t)b * Cz + c] + pos_start[c] + ltab[c] + pos1[c];
        ((float*)out)[((size_t)(r0 + rr)) * Cz + c] = val;
      } else {
        ((unsigned short*)out)[((size_t)(r0 + rr)) * Cz + c] = f2bf(s[rr]);
      }
    }
  }
}

// ---------------------------------------------------------------- launch
extern "C" void kernel_launch(void* const* d_in, const int* in_sizes, int n_in,
                              void* d_out, int out_size, void* d_ws, size_t ws_size,
                              hipStream_t stream)
{
  (void)in_sizes; (void)n_in; (void)out_size; (void)ws_size;
  const float* x_blcv   = (const float*)d_in[0];
  const float* poc_ctx  = (const float*)d_in[1];
  const float* poc_cond = (const float*)d_in[2];
  const float* word_w   = (const float*)d_in[3];
  const float* word_b   = (const float*)d_in[4];
  const float* poc_w    = (const float*)d_in[5];
  const float* poc_b    = (const float*)d_in[6];
  const float* pos_start= (const float*)d_in[7];
  const float* pos_1lc  = (const float*)d_in[8];
  const float* lvl_tab  = (const float*)d_in[9];
  const float* ada_w    = (const float*)d_in[10];
  const float* ada_b    = (const float*)d_in[11];
  const float* ada_gss  = (const float*)d_in[12];
  const float* q_w      = (const float*)d_in[13];
  const float* q_b      = (const float*)d_in[14];
  const float* kv_w     = (const float*)d_in[15];
  const float* kv_b     = (const float*)d_in[16];
  const float* proj_w   = (const float*)d_in[17];
  const float* proj_b   = (const float*)d_in[18];
  const float* fc1_w    = (const float*)d_in[19];
  const float* fc1_b    = (const float*)d_in[20];
  const float* fc2_w    = (const float*)d_in[21];
  const float* fc2_b    = (const float*)d_in[22];
  const float* head_ada_w = (const float*)d_in[23];
  const float* head_ada_b = (const float*)d_in[24];
  const float* head_w   = (const float*)d_in[25];
  const float* head_b   = (const float*)d_in[26];

  char* p = (char*)d_ws;
  auto carve = [&](size_t bytes) { void* r = (void*)p; p += (bytes + 255) & ~(size_t)255; return r; };
  float* x            = (float*)carve((size_t)BL * Cz * 4);
  unsigned short* xn  = (unsigned short*)carve((size_t)BL * Cz * 2);
  unsigned short* poc = (unsigned short*)carve((size_t)BL * Cz * 2);
  unsigned short* qbf = (unsigned short*)carve((size_t)BL * Cz * 2);
  unsigned short* kbuf= (unsigned short*)carve((size_t)BL * Cz * 2);
  unsigned short* vtb = (unsigned short*)carve((size_t)BL * Cz * 2);
  unsigned short* ob  = (unsigned short*)carve((size_t)BL * Cz * 2);
  unsigned short* hdn = (unsigned short*)carve((size_t)BL * MLPz * 2);
  unsigned short* wt  = (unsigned short*)carve((size_t)12582912 * 2);
  float* cond  = (float*)carve(32 * 1024 * 4);
  float* siluc = (float*)carve(32 * 1024 * 4);
  float* gss   = (float*)carve(32 * 6144 * 4);
  float* ss    = (float*)carve(32 * 2048 * 4);

  unsigned short* qwt  = wt;
  unsigned short* kvwt = wt + 1048576;
  unsigned short* pjwt = wt + 3145728;
  unsigned short* f1wt = wt + 4194304;
  unsigned short* f2wt = wt + 8388608;

  cond_k<<<dim3(4, 32), 256, 0, stream>>>(poc_cond, poc_w, poc_b, cond, siluc);
  smallmm_k<<<dim3(24, 32), 256, 0, stream>>>(siluc, ada_w, ada_b, gss, 6144);
  smallmm_k<<<dim3(8, 32), 256, 0, stream>>>(siluc, head_ada_w, head_ada_b, ss, 2048);
  embed_k<0><<<3200, 256, 0, stream>>>(x_blcv, word_w, word_b, cond, pos_start, pos_1lc, lvl_tab, x);
  embed_k<1><<<3200, 256, 0, stream>>>(poc_ctx, word_w, word_b, cond, pos_start, pos_1lc, lvl_tab, poc);

  for (int d = 0; d < 8; d++) {
    const float* ag = ada_gss + (size_t)d * 6144;
    tconv_k<<<dim3(16, 16), 256, 0, stream>>>(q_w + (size_t)d * 1048576, qwt, 1024, 1024);
    tconv_k<<<dim3(32, 16), 256, 0, stream>>>(kv_w + (size_t)d * 2097152, kvwt, 1024, 2048);
    tconv_k<<<dim3(16, 16), 256, 0, stream>>>(proj_w + (size_t)d * 1048576, pjwt, 1024, 1024);
    tconv_k<<<dim3(64, 16), 256, 0, stream>>>(fc1_w + (size_t)d * 4194304, f1wt, 1024, 4096);
    tconv_k<<<dim3(16, 64), 256, 0, stream>>>(fc2_w + (size_t)d * 4194304, f2wt, 4096, 1024);

    ln_k<<<BL, 256, 0, stream>>>(x, xn, ag + 2 * 1024, gss + 2 * 1024, 6144,
                                 ag + 4 * 1024, gss + 4 * 1024, 6144);
    gemm2_k<EP_BF16><<<dim3(100, 8), 256, 0, stream>>>(
        xn, qwt, q_b + d * 1024, qbf, nullptr, nullptr, nullptr, nullptr, 1024, 1024);
    gemm2_k<EP_KV><<<dim3(100, 16), 256, 0, stream>>>(
        poc, kvwt, kv_b + d * 2048, kbuf, nullptr, nullptr, nullptr, vtb, 2048, 1024);
    attn3_k<<<dim3(512, 4), 512, 0, stream>>>(qbf, kbuf, vtb, ob);
    gemm2_k<EP_RESID><<<dim3(100, 8), 256, 0, stream>>>(
        ob, pjwt, proj_b + d * 1024, nullptr, x, ag + 0, gss + 0, nullptr, 1024, 1024);
    ln_k<<<BL, 256, 0, stream>>>(x, xn, ag + 3 * 1024, gss + 3 * 1024, 6144,
                                 ag + 5 * 1024, gss + 5 * 1024, 6144);
    gemm2_k<EP_GELU><<<dim3(100, 32), 256, 0, stream>>>(
        xn, f1wt, fc1_b + d * 4096, hdn, nullptr, nullptr, nullptr, nullptr, 4096, 1024);
    gemm2_k<EP_RESID><<<dim3(100, 8), 256, 0, stream>>>(
        hdn, f2wt, fc2_b + d * 1024, nullptr, x, ag + 1024, gss + 1024, nullptr, 1024, 4096);
  }
  ln_k<<<BL, 256, 0, stream>>>(x, xn, nullptr, ss, 2048, nullptr, ss + 1024, 2048);
  tconv_k<<<dim3(64, 16), 256, 0, stream>>>(head_w, wt, 1024, 4096);
  gemm2_k<EP_F32><<<dim3(100, 32), 256, 0, stream>>>(
      xn, wt, head_b, d_out, nullptr, nullptr, nullptr, nullptr, 4096, 1024);
}